// Round 8
// baseline (299.994 us; speedup 1.0000x reference)
//
#include <hip/hip_runtime.h>
#include <hip/hip_bf16.h>
#include <stdint.h>

typedef unsigned short u16;
typedef __bf16 bf16x8 __attribute__((ext_vector_type(8)));
typedef short s16x4 __attribute__((ext_vector_type(4)));
typedef float f32x4 __attribute__((ext_vector_type(4)));
typedef u16 u16x4v __attribute__((ext_vector_type(4)));

#define AS1 __attribute__((address_space(1)))
#define AS3 __attribute__((address_space(3)))

__device__ __forceinline__ void gld_lds16(const u16* g, u16* l) {
    __builtin_amdgcn_global_load_lds((const AS1 uint32_t*)g, (AS3 uint32_t*)l, 16, 0, 0);
}

__device__ __forceinline__ u16 f2bf(float f) {
    union { float f; uint32_t u; } v; v.f = f;
    uint32_t u = v.u;
    return (u16)((u + 0x7FFFu + ((u >> 16) & 1u)) >> 16);
}

// exp2 scale folded into Q at gemm1 epilogue: 0.125 * log2(e)
#define QSCALE 0.18033688011112042f

// ---------------- cast fp32 -> bf16 (vectorized) ----------------
__global__ void cast_f32_bf16(const float* __restrict__ in, u16* __restrict__ out, int n4) {
    int i = blockIdx.x * blockDim.x + threadIdx.x;
    if (i < n4) {
        float4 f = ((const float4*)in)[i];
        u16x4v o;
        o.x = f2bf(f.x); o.y = f2bf(f.y); o.z = f2bf(f.z); o.w = f2bf(f.w);
        ((u16x4v*)out)[i] = o;
    }
}

// ---------------- bt-GEMM: C[m,n] = sum_k A[m,k]*B[n,k] + bias[n] ----------------
// MODE 0: fp32 out, row-major ldc.
// MODE 1: qkv split epilogue -> qb (bf16, prescaled), kb (bf16), vT (bf16, [h][hd][8192]).
template <int MODE>
__global__ __launch_bounds__(256, 2) void gemm_bt(
    const u16* __restrict__ A, const u16* __restrict__ B,
    const float* __restrict__ bias, float* __restrict__ Cf,
    u16* __restrict__ qb, u16* __restrict__ kb, u16* __restrict__ vT,
    int K, int ldc)
{
    __shared__ __align__(16) u16 As[128 * 32];
    __shared__ __align__(16) u16 Bs[128 * 32];
    const int tid = threadIdx.x;
    const int lane = tid & 63;
    const int w = tid >> 6;
    const int wm = (w >> 1) << 6;
    const int wn = (w & 1) << 6;
    const int r = lane & 15;
    const int q = lane >> 4;
    const int m0 = blockIdx.y << 7;
    const int n0 = blockIdx.x << 7;

    const f32x4 zero4 = {0.f, 0.f, 0.f, 0.f};
    f32x4 acc[4][4];
#pragma unroll
    for (int i = 0; i < 4; ++i)
#pragma unroll
        for (int j = 0; j < 4; ++j) acc[i][j] = zero4;

    const int nk = K >> 5;
    for (int kt = 0; kt < nk; ++kt) {
        const int kk = kt << 5;
#pragma unroll
        for (int p = 0; p < 2; ++p) {
            const int idx = (p << 8) + tid;
            const int row = idx >> 2;
            const int cg = ((idx & 3) - (row >> 1)) & 3;
            gld_lds16(A + (m0 + row) * K + kk + (cg << 3), &As[idx << 3]);
            gld_lds16(B + (n0 + row) * K + kk + (cg << 3), &Bs[idx << 3]);
        }
        __syncthreads();
        bf16x8 af[4], bf[4];
#pragma unroll
        for (int i = 0; i < 4; ++i) {
            const int ra = wm + (i << 4) + r;
            af[i] = *(const bf16x8*)&As[((ra << 2) + ((q + (ra >> 1)) & 3)) << 3];
            const int rb = wn + (i << 4) + r;
            bf[i] = *(const bf16x8*)&Bs[((rb << 2) + ((q + (rb >> 1)) & 3)) << 3];
        }
#pragma unroll
        for (int i = 0; i < 4; ++i)
#pragma unroll
            for (int j = 0; j < 4; ++j)
                acc[i][j] = __builtin_amdgcn_mfma_f32_16x16x32_bf16(af[i], bf[j], acc[i][j], 0, 0, 0);
        __syncthreads();
    }

#pragma unroll
    for (int j = 0; j < 4; ++j) {
        const int col = n0 + wn + (j << 4) + r;
        const float bv = bias[col];
        if (MODE == 0) {
#pragma unroll
            for (int i = 0; i < 4; ++i)
#pragma unroll
                for (int ii = 0; ii < 4; ++ii) {
                    const int rowg = m0 + wm + (i << 4) + (q << 2) + ii;
                    Cf[rowg * ldc + col] = acc[i][j][ii] + bv;
                }
        } else {
            // wave-uniform region decode per j-group (16 cols never straddle 64/192 boundaries)
            const int c0 = n0 + wn + (j << 4);
            const int h = c0 / 192;
            const int rem = c0 - h * 192;
            const int region = rem >> 6;
            const int colp = (h << 6) + (rem - (region << 6)) + r;
            if (region == 0) {
#pragma unroll
                for (int i = 0; i < 4; ++i)
#pragma unroll
                    for (int ii = 0; ii < 4; ++ii) {
                        const int rowg = m0 + wm + (i << 4) + (q << 2) + ii;
                        qb[rowg * 1024 + colp] = f2bf((acc[i][j][ii] + bv) * QSCALE);
                    }
            } else if (region == 1) {
#pragma unroll
                for (int i = 0; i < 4; ++i)
#pragma unroll
                    for (int ii = 0; ii < 4; ++ii) {
                        const int rowg = m0 + wm + (i << 4) + (q << 2) + ii;
                        kb[rowg * 1024 + colp] = f2bf(acc[i][j][ii] + bv);
                    }
            } else {
                // V transposed: vT[colp][rowg], rowg contiguous -> packed 8B stores
#pragma unroll
                for (int i = 0; i < 4; ++i) {
                    const int rowg0 = m0 + wm + (i << 4) + (q << 2);
                    u16x4v vv;
                    vv.x = f2bf(acc[i][j][0] + bv);
                    vv.y = f2bf(acc[i][j][1] + bv);
                    vv.z = f2bf(acc[i][j][2] + bv);
                    vv.w = f2bf(acc[i][j][3] + bv);
                    *(u16x4v*)&vT[(size_t)colp * 8192 + rowg0] = vv;
                }
            }
        }
    }
}

// ---------------- flash attention, S^T formulation, double-buffered K/V ----------------
// qb/kb: [8192][1024] bf16 (head h at cols h*64..h*64+63), Q pre-scaled.
// vT: [16][64][8192] bf16 (V transposed per head).
// grid: (h fastest, qtile, b) -> XCD-local K/V reuse.
// S^T = K Q^T -> C-layout == B-frag of mfma_16x16x16bf16_1k; P stays in regs.
// l via ones-A MFMA (column sums of P).
// LDS: 32 KB total — Q staging region reused as KV buffer B after fragment load.
// amdgpu_waves_per_eu(4,4): pin exactly 4 waves/EU -> VGPR budget 128, no
// heuristic clamp to 64 (R7's spill: WRITE_SIZE 41 MB of scratch traffic).
__device__ __forceinline__ void stage_kv(
    const u16* __restrict__ kb, const u16* __restrict__ vT, u16* __restrict__ KV,
    int tid, int h, size_t rowbase, int k0)
{
#pragma unroll
    for (int p = 0; p < 2; ++p) {
        const int idx = (p << 8) + tid;
        const int row = idx >> 3;
        const int cg = ((idx & 7) - row) & 7;
        gld_lds16(kb + (rowbase + k0 + row) * 1024 + (h << 6) + (cg << 3), &KV[idx << 3]);
    }
#pragma unroll
    for (int p = 0; p < 2; ++p) {
        const int idx = (p << 8) + tid;
        const int hd = idx >> 3;
        const int pc = idx & 7;
        const int lc = (pc - hd - (hd >> 3)) & 7;
        gld_lds16(vT + (size_t)((h << 6) + hd) * 8192 + rowbase + k0 + (lc << 3),
                  &KV[4096 + (idx << 3)]);
    }
}

__global__ __launch_bounds__(256)
__attribute__((amdgpu_waves_per_eu(4, 4)))
void attn(
    const u16* __restrict__ qb, const u16* __restrict__ kb,
    const u16* __restrict__ vT, u16* __restrict__ vals)
{
    // S[0:8192)   : Q staging at init, then KV buffer B (odd kt)
    // S[8192:16384): KV buffer A (even kt)
    // K part: [row][64], 16B chunks, phys chunk = (L+row)&7
    // V part (at +4096): [hd][kv], 16B chunks, phys chunk = (L+hd+(hd>>3))&7
    __shared__ __align__(16) u16 S[16384];

    const int tid = threadIdx.x;
    const int lane = tid & 63;
    const int w = tid >> 6;
    const int r = lane & 15;
    const int q = lane >> 4;
    const int h = blockIdx.x;
    const int q0 = blockIdx.y << 7;
    const int b = blockIdx.z;
    const size_t rowbase = (size_t)b * 2048;

    // stage Q (128 rows x 8 chunks of 8 u16) into S[0:8192)
#pragma unroll
    for (int p = 0; p < 4; ++p) {
        const int idx = (p << 8) + tid;
        const int row = idx >> 3;
        const int cg = ((idx & 7) - row) & 7;
        gld_lds16(qb + (rowbase + q0 + row) * 1024 + (h << 6) + (cg << 3), &S[idx << 3]);
    }
    // stage K/V for kt=0 into buffer A
    stage_kv(kb, vT, S + 8192, tid, h, rowbase, 0);
    __syncthreads();

    // Q fragments (loop-invariant): bq[ks][nt], lane holds Q[qrow=32w+16nt+r][32ks+8q+j]
    bf16x8 bq[2][2];
#pragma unroll
    for (int ks = 0; ks < 2; ++ks) {
        const int L = (ks << 2) + q;
#pragma unroll
        for (int nt = 0; nt < 2; ++nt) {
            const int row = (w << 5) + (nt << 4) + r;
            bq[ks][nt] = *(const bf16x8*)&S[(row << 6) + (((L + row) & 7) << 3)];
        }
    }
    __syncthreads();  // all waves done reading Q before buffer B is overwritten

    const f32x4 zero4 = {0.f, 0.f, 0.f, 0.f};
    f32x4 oacc[4][2];      // [ht][nt] : O^T[hd=16ht+4q+i][qrow=32w+16nt+r]
    f32x4 lacc[2];         // ones-MFMA column sums: lacc[nt][*] = l for qcol r
#pragma unroll
    for (int ht = 0; ht < 4; ++ht)
#pragma unroll
        for (int nt = 0; nt < 2; ++nt) oacc[ht][nt] = zero4;
    lacc[0] = zero4; lacc[1] = zero4;

    const s16x4 ones = {0x3F80, 0x3F80, 0x3F80, 0x3F80};  // bf16 1.0 x4

    for (int kt = 0; kt < 32; ++kt) {
        const int cur = kt & 1;
        if (kt > 0) __syncthreads();   // drains prefetch (issued a full kt ago) + orders buffers
        u16* bufP = (cur == 0) ? (S + 0) : (S + 8192);       // prefetch target (kt+1)
        const u16* bufC = (cur == 0) ? (S + 8192) : (S + 0); // compute source (kt)
        if (kt < 31) stage_kv(kb, vT, bufP, tid, h, rowbase, (kt + 1) << 6);
        const u16* Ks = bufC;
        const u16* VTs = bufC + 4096;

        // S^T tiles: sacc[mt][nt], mt = kv-tile (4x16), nt = qrow-tile (2x16)
        f32x4 sacc[4][2];
#pragma unroll
        for (int mt = 0; mt < 4; ++mt)
#pragma unroll
            for (int nt = 0; nt < 2; ++nt) sacc[mt][nt] = zero4;
#pragma unroll
        for (int ks = 0; ks < 2; ++ks) {
            const int L = (ks << 2) + q;
            bf16x8 ak[4];
#pragma unroll
            for (int mt = 0; mt < 4; ++mt) {
                const int row = (mt << 4) + r;
                ak[mt] = *(const bf16x8*)&Ks[(row << 6) + (((L + row) & 7) << 3)];
            }
#pragma unroll
            for (int mt = 0; mt < 4; ++mt)
#pragma unroll
                for (int nt = 0; nt < 2; ++nt)
                    sacc[mt][nt] = __builtin_amdgcn_mfma_f32_16x16x32_bf16(ak[mt], bq[ks][nt], sacc[mt][nt], 0, 0, 0);
        }

        // p = exp2(s); pack to bf16 B-frags; l via ones-MFMA (column sums)
        s16x4 pb[4][2];
#pragma unroll
        for (int mt = 0; mt < 4; ++mt) {
#pragma unroll
            for (int nt = 0; nt < 2; ++nt) {
                const float e0 = __builtin_amdgcn_exp2f(sacc[mt][nt][0]);
                const float e1 = __builtin_amdgcn_exp2f(sacc[mt][nt][1]);
                const float e2 = __builtin_amdgcn_exp2f(sacc[mt][nt][2]);
                const float e3 = __builtin_amdgcn_exp2f(sacc[mt][nt][3]);
                union { __hip_bfloat162 h2[2]; s16x4 v; } u;
                u.h2[0] = __float22bfloat162_rn(float2{e0, e1});
                u.h2[1] = __float22bfloat162_rn(float2{e2, e3});
                pb[mt][nt] = u.v;
                lacc[nt] = __builtin_amdgcn_mfma_f32_16x16x16bf16_1k(ones, pb[mt][nt], lacc[nt], 0, 0, 0);
            }
        }

        // O^T += V^T P^T  (A = V^T frag from LDS b64, B = pb from registers)
#pragma unroll
        for (int mt = 0; mt < 4; ++mt) {
            s16x4 av[4];
#pragma unroll
            for (int ht = 0; ht < 4; ++ht) {
                const int hd = (ht << 4) + r;
                const int chunk = (mt << 1) + (q >> 1);
                const int pc = (chunk + hd + (hd >> 3)) & 7;
                av[ht] = *(const s16x4*)&VTs[(hd << 6) + (pc << 3) + ((q & 1) << 2)];
            }
#pragma unroll
            for (int ht = 0; ht < 4; ++ht)
#pragma unroll
                for (int nt = 0; nt < 2; ++nt)
                    oacc[ht][nt] = __builtin_amdgcn_mfma_f32_16x16x16bf16_1k(av[ht], pb[mt][nt], oacc[ht][nt], 0, 0, 0);
        }
    }

    // epilogue: l directly from lacc (all rows identical); O^T/l -> vals (packed b64)
#pragma unroll
    for (int nt = 0; nt < 2; ++nt) {
        const float inv = 1.f / lacc[nt][0];
        const int srow = q0 + (w << 5) + (nt << 4) + r;
#pragma unroll
        for (int ht = 0; ht < 4; ++ht) {
            u16x4v vv;
            vv.x = f2bf(oacc[ht][nt][0] * inv);
            vv.y = f2bf(oacc[ht][nt][1] * inv);
            vv.z = f2bf(oacc[ht][nt][2] * inv);
            vv.w = f2bf(oacc[ht][nt][3] * inv);
            const int col = (h << 6) + (ht << 4) + (q << 2);
            *(u16x4v*)&vals[(rowbase + srow) * 1024 + col] = vv;
        }
    }
}

// ---------------- launcher ----------------
extern "C" void kernel_launch(void* const* d_in, const int* in_sizes, int n_in,
                              void* d_out, int out_size, void* d_ws, size_t ws_size,
                              hipStream_t stream) {
    (void)in_sizes; (void)n_in; (void)out_size; (void)ws_size;
    const float* x     = (const float*)d_in[0];   // [4,2048,1024]
    const float* w_qkv = (const float*)d_in[1];   // [3072,1024]
    const float* b_qkv = (const float*)d_in[2];   // [3072]
    const float* w_o   = (const float*)d_in[3];   // [1024,1024]
    const float* b_o   = (const float*)d_in[4];   // [1024]
    float* out = (float*)d_out;                   // [4,2048,1024]

    char* ws = (char*)d_ws;
    u16* xb    = (u16*)(ws);                          // 16 MB  [8192,1024]
    u16* wqkvb = (u16*)(ws + (size_t)(16 << 20));     //  6 MB  [3072,1024]
    u16* wob   = (u16*)(ws + (size_t)(22 << 20));     //  2 MB  [1024,1024]
    u16* qb    = (u16*)(ws + (size_t)(24 << 20));     // 16 MB  [8192,1024]
    u16* kb    = (u16*)(ws + (size_t)(40 << 20));     // 16 MB  [8192,1024]
    u16* vTb   = (u16*)(ws + (size_t)(56 << 20));     // 16 MB  [16,64,8192]
    u16* valsb = (u16*)(ws + (size_t)(72 << 20));     // 16 MB  [8192,1024]

    cast_f32_bf16<<<8192, 256, 0, stream>>>(x, xb, 2097152);
    cast_f32_bf16<<<3072, 256, 0, stream>>>(w_qkv, wqkvb, 786432);
    cast_f32_bf16<<<1024, 256, 0, stream>>>(w_o, wob, 262144);

    // qkv = x @ w_qkv^T + b_qkv -> split qb (prescaled) / kb / vT
    gemm_bt<1><<<dim3(24, 64), 256, 0, stream>>>(xb, wqkvb, b_qkv, nullptr,
                                                 qb, kb, vTb, 1024, 3072);

    // attention -> vals (bf16); grid: h fastest for XCD-local K/V reuse
    attn<<<dim3(16, 16, 4), 256, 0, stream>>>(qb, kb, vTb, valsb);

    // out = vals @ w_o^T + b_o  (fp32 out)
    gemm_bt<0><<<dim3(8, 64), 256, 0, stream>>>(valsb, wob, b_o, out,
                                                nullptr, nullptr, nullptr, 1024, 1024);
}

// Round 9
// 281.829 us; speedup vs baseline: 1.0645x; 1.0645x over previous
//
#include <hip/hip_runtime.h>
#include <hip/hip_bf16.h>
#include <stdint.h>

typedef unsigned short u16;
typedef __bf16 bf16x8 __attribute__((ext_vector_type(8)));
typedef short s16x4 __attribute__((ext_vector_type(4)));
typedef float f32x4 __attribute__((ext_vector_type(4)));
typedef u16 u16x4v __attribute__((ext_vector_type(4)));

#define AS1 __attribute__((address_space(1)))
#define AS3 __attribute__((address_space(3)))

__device__ __forceinline__ void gld_lds16(const u16* g, u16* l) {
    __builtin_amdgcn_global_load_lds((const AS1 uint32_t*)g, (AS3 uint32_t*)l, 16, 0, 0);
}

__device__ __forceinline__ u16 f2bf(float f) {
    union { float f; uint32_t u; } v; v.f = f;
    uint32_t u = v.u;
    return (u16)((u + 0x7FFFu + ((u >> 16) & 1u)) >> 16);
}

// exp2 scale folded into Q at gemm1 epilogue: 0.125 * log2(e)
#define QSCALE 0.18033688011112042f

// ---------------- cast fp32 -> bf16 (vectorized) ----------------
__global__ void cast_f32_bf16(const float* __restrict__ in, u16* __restrict__ out, int n4) {
    int i = blockIdx.x * blockDim.x + threadIdx.x;
    if (i < n4) {
        float4 f = ((const float4*)in)[i];
        u16x4v o;
        o.x = f2bf(f.x); o.y = f2bf(f.y); o.z = f2bf(f.z); o.w = f2bf(f.w);
        ((u16x4v*)out)[i] = o;
    }
}

// ---------------- bt-GEMM: C[m,n] = sum_k A[m,k]*B[n,k] + bias[n] ----------------
// MODE 0: fp32 out, row-major ldc.
// MODE 1: qkv split epilogue -> qb (bf16, prescaled), kb (bf16), vT (bf16, [h][hd][8192]).
template <int MODE>
__global__ __launch_bounds__(256, 2) void gemm_bt(
    const u16* __restrict__ A, const u16* __restrict__ B,
    const float* __restrict__ bias, float* __restrict__ Cf,
    u16* __restrict__ qb, u16* __restrict__ kb, u16* __restrict__ vT,
    int K, int ldc)
{
    __shared__ __align__(16) u16 As[128 * 32];
    __shared__ __align__(16) u16 Bs[128 * 32];
    const int tid = threadIdx.x;
    const int lane = tid & 63;
    const int w = tid >> 6;
    const int wm = (w >> 1) << 6;
    const int wn = (w & 1) << 6;
    const int r = lane & 15;
    const int q = lane >> 4;
    const int m0 = blockIdx.y << 7;
    const int n0 = blockIdx.x << 7;

    const f32x4 zero4 = {0.f, 0.f, 0.f, 0.f};
    f32x4 acc[4][4];
#pragma unroll
    for (int i = 0; i < 4; ++i)
#pragma unroll
        for (int j = 0; j < 4; ++j) acc[i][j] = zero4;

    const int nk = K >> 5;
    for (int kt = 0; kt < nk; ++kt) {
        const int kk = kt << 5;
#pragma unroll
        for (int p = 0; p < 2; ++p) {
            const int idx = (p << 8) + tid;
            const int row = idx >> 2;
            const int cg = ((idx & 3) - (row >> 1)) & 3;
            gld_lds16(A + (m0 + row) * K + kk + (cg << 3), &As[idx << 3]);
            gld_lds16(B + (n0 + row) * K + kk + (cg << 3), &Bs[idx << 3]);
        }
        __syncthreads();
        bf16x8 af[4], bf[4];
#pragma unroll
        for (int i = 0; i < 4; ++i) {
            const int ra = wm + (i << 4) + r;
            af[i] = *(const bf16x8*)&As[((ra << 2) + ((q + (ra >> 1)) & 3)) << 3];
            const int rb = wn + (i << 4) + r;
            bf[i] = *(const bf16x8*)&Bs[((rb << 2) + ((q + (rb >> 1)) & 3)) << 3];
        }
#pragma unroll
        for (int i = 0; i < 4; ++i)
#pragma unroll
            for (int j = 0; j < 4; ++j)
                acc[i][j] = __builtin_amdgcn_mfma_f32_16x16x32_bf16(af[i], bf[j], acc[i][j], 0, 0, 0);
        __syncthreads();
    }

#pragma unroll
    for (int j = 0; j < 4; ++j) {
        const int col = n0 + wn + (j << 4) + r;
        const float bv = bias[col];
        if (MODE == 0) {
#pragma unroll
            for (int i = 0; i < 4; ++i)
#pragma unroll
                for (int ii = 0; ii < 4; ++ii) {
                    const int rowg = m0 + wm + (i << 4) + (q << 2) + ii;
                    Cf[rowg * ldc + col] = acc[i][j][ii] + bv;
                }
        } else {
            // wave-uniform region decode per j-group (16 cols never straddle 64/192 boundaries)
            const int c0 = n0 + wn + (j << 4);
            const int h = c0 / 192;
            const int rem = c0 - h * 192;
            const int region = rem >> 6;
            const int colp = (h << 6) + (rem - (region << 6)) + r;
            if (region == 0) {
#pragma unroll
                for (int i = 0; i < 4; ++i)
#pragma unroll
                    for (int ii = 0; ii < 4; ++ii) {
                        const int rowg = m0 + wm + (i << 4) + (q << 2) + ii;
                        qb[rowg * 1024 + colp] = f2bf((acc[i][j][ii] + bv) * QSCALE);
                    }
            } else if (region == 1) {
#pragma unroll
                for (int i = 0; i < 4; ++i)
#pragma unroll
                    for (int ii = 0; ii < 4; ++ii) {
                        const int rowg = m0 + wm + (i << 4) + (q << 2) + ii;
                        kb[rowg * 1024 + colp] = f2bf(acc[i][j][ii] + bv);
                    }
            } else {
                // V transposed: vT[colp][rowg], rowg contiguous -> packed 8B stores
#pragma unroll
                for (int i = 0; i < 4; ++i) {
                    const int rowg0 = m0 + wm + (i << 4) + (q << 2);
                    u16x4v vv;
                    vv.x = f2bf(acc[i][j][0] + bv);
                    vv.y = f2bf(acc[i][j][1] + bv);
                    vv.z = f2bf(acc[i][j][2] + bv);
                    vv.w = f2bf(acc[i][j][3] + bv);
                    *(u16x4v*)&vT[(size_t)colp * 8192 + rowg0] = vv;
                }
            }
        }
    }
}

// ---------------- flash attention, S^T formulation, double-buffered K/V ----------------
// qb/kb: [8192][1024] bf16 (head h at cols h*64..h*64+63), Q pre-scaled.
// vT: [16][64][8192] bf16 (V transposed per head).
// grid: (h fastest, qtile, b) -> XCD-local K/V reuse.
// S^T = K Q^T -> C-layout == B-frag of mfma_16x16x16bf16_1k; P stays in regs.
// l via ones-A MFMA (column sums of P).
// LDS: 32 KB total — Q staging region reused as KV buffer B after fragment load.
// __launch_bounds__(256,3): VGPR budget 170. R6 measured this structure at
// VGPR=84, no spill; 84<=128 keeps 4 blocks/CU resident (grid = exactly 4/CU).
// DO NOT use (256,4): allocator clamps to 64 VGPR and spills ~26 MB/dispatch
// (R7/R8 measured). amdgpu_waves_per_eu(4,4) is silently ignored (R8).
__device__ __forceinline__ void stage_kv(
    const u16* __restrict__ kb, const u16* __restrict__ vT, u16* __restrict__ KV,
    int tid, int h, size_t rowbase, int k0)
{
#pragma unroll
    for (int p = 0; p < 2; ++p) {
        const int idx = (p << 8) + tid;
        const int row = idx >> 3;
        const int cg = ((idx & 7) - row) & 7;
        gld_lds16(kb + (rowbase + k0 + row) * 1024 + (h << 6) + (cg << 3), &KV[idx << 3]);
    }
#pragma unroll
    for (int p = 0; p < 2; ++p) {
        const int idx = (p << 8) + tid;
        const int hd = idx >> 3;
        const int pc = idx & 7;
        const int lc = (pc - hd - (hd >> 3)) & 7;
        gld_lds16(vT + (size_t)((h << 6) + hd) * 8192 + rowbase + k0 + (lc << 3),
                  &KV[4096 + (idx << 3)]);
    }
}

__global__ __launch_bounds__(256, 3) void attn(
    const u16* __restrict__ qb, const u16* __restrict__ kb,
    const u16* __restrict__ vT, u16* __restrict__ vals)
{
    // S[0:8192)   : Q staging at init, then KV buffer B (odd kt)
    // S[8192:16384): KV buffer A (even kt)
    // K part: [row][64], 16B chunks, phys chunk = (L+row)&7
    // V part (at +4096): [hd][kv], 16B chunks, phys chunk = (L+hd+(hd>>3))&7
    __shared__ __align__(16) u16 S[16384];

    const int tid = threadIdx.x;
    const int lane = tid & 63;
    const int w = tid >> 6;
    const int r = lane & 15;
    const int q = lane >> 4;
    const int h = blockIdx.x;
    const int q0 = blockIdx.y << 7;
    const int b = blockIdx.z;
    const size_t rowbase = (size_t)b * 2048;

    // stage Q (128 rows x 8 chunks of 8 u16) into S[0:8192)
#pragma unroll
    for (int p = 0; p < 4; ++p) {
        const int idx = (p << 8) + tid;
        const int row = idx >> 3;
        const int cg = ((idx & 7) - row) & 7;
        gld_lds16(qb + (rowbase + q0 + row) * 1024 + (h << 6) + (cg << 3), &S[idx << 3]);
    }
    // stage K/V for kt=0 into buffer A
    stage_kv(kb, vT, S + 8192, tid, h, rowbase, 0);
    __syncthreads();

    // Q fragments (loop-invariant): bq[ks][nt], lane holds Q[qrow=32w+16nt+r][32ks+8q+j]
    bf16x8 bq[2][2];
#pragma unroll
    for (int ks = 0; ks < 2; ++ks) {
        const int L = (ks << 2) + q;
#pragma unroll
        for (int nt = 0; nt < 2; ++nt) {
            const int row = (w << 5) + (nt << 4) + r;
            bq[ks][nt] = *(const bf16x8*)&S[(row << 6) + (((L + row) & 7) << 3)];
        }
    }
    __syncthreads();  // all waves done reading Q before buffer B is overwritten

    const f32x4 zero4 = {0.f, 0.f, 0.f, 0.f};
    f32x4 oacc[4][2];      // [ht][nt] : O^T[hd=16ht+4q+i][qrow=32w+16nt+r]
    f32x4 lacc[2];         // ones-MFMA column sums: lacc[nt][*] = l for qcol r
#pragma unroll
    for (int ht = 0; ht < 4; ++ht)
#pragma unroll
        for (int nt = 0; nt < 2; ++nt) oacc[ht][nt] = zero4;
    lacc[0] = zero4; lacc[1] = zero4;

    const s16x4 ones = {0x3F80, 0x3F80, 0x3F80, 0x3F80};  // bf16 1.0 x4

    for (int kt = 0; kt < 32; ++kt) {
        const int cur = kt & 1;
        if (kt > 0) __syncthreads();   // drains prefetch (issued a full kt ago) + orders buffers
        u16* bufP = (cur == 0) ? (S + 0) : (S + 8192);       // prefetch target (kt+1)
        const u16* bufC = (cur == 0) ? (S + 8192) : (S + 0); // compute source (kt)
        if (kt < 31) stage_kv(kb, vT, bufP, tid, h, rowbase, (kt + 1) << 6);
        const u16* Ks = bufC;
        const u16* VTs = bufC + 4096;

        // S^T tiles: sacc[mt][nt], mt = kv-tile (4x16), nt = qrow-tile (2x16)
        f32x4 sacc[4][2];
#pragma unroll
        for (int mt = 0; mt < 4; ++mt)
#pragma unroll
            for (int nt = 0; nt < 2; ++nt) sacc[mt][nt] = zero4;
#pragma unroll
        for (int ks = 0; ks < 2; ++ks) {
            const int L = (ks << 2) + q;
            bf16x8 ak[4];
#pragma unroll
            for (int mt = 0; mt < 4; ++mt) {
                const int row = (mt << 4) + r;
                ak[mt] = *(const bf16x8*)&Ks[(row << 6) + (((L + row) & 7) << 3)];
            }
#pragma unroll
            for (int mt = 0; mt < 4; ++mt)
#pragma unroll
                for (int nt = 0; nt < 2; ++nt)
                    sacc[mt][nt] = __builtin_amdgcn_mfma_f32_16x16x32_bf16(ak[mt], bq[ks][nt], sacc[mt][nt], 0, 0, 0);
        }

        // p = exp2(s); pack to bf16 B-frags; l via ones-MFMA (column sums)
        s16x4 pb[4][2];
#pragma unroll
        for (int mt = 0; mt < 4; ++mt) {
#pragma unroll
            for (int nt = 0; nt < 2; ++nt) {
                const float e0 = __builtin_amdgcn_exp2f(sacc[mt][nt][0]);
                const float e1 = __builtin_amdgcn_exp2f(sacc[mt][nt][1]);
                const float e2 = __builtin_amdgcn_exp2f(sacc[mt][nt][2]);
                const float e3 = __builtin_amdgcn_exp2f(sacc[mt][nt][3]);
                union { __hip_bfloat162 h2[2]; s16x4 v; } u;
                u.h2[0] = __float22bfloat162_rn(float2{e0, e1});
                u.h2[1] = __float22bfloat162_rn(float2{e2, e3});
                pb[mt][nt] = u.v;
                lacc[nt] = __builtin_amdgcn_mfma_f32_16x16x16bf16_1k(ones, pb[mt][nt], lacc[nt], 0, 0, 0);
            }
        }

        // O^T += V^T P^T  (A = V^T frag from LDS b64, B = pb from registers)
#pragma unroll
        for (int mt = 0; mt < 4; ++mt) {
            s16x4 av[4];
#pragma unroll
            for (int ht = 0; ht < 4; ++ht) {
                const int hd = (ht << 4) + r;
                const int chunk = (mt << 1) + (q >> 1);
                const int pc = (chunk + hd + (hd >> 3)) & 7;
                av[ht] = *(const s16x4*)&VTs[(hd << 6) + (pc << 3) + ((q & 1) << 2)];
            }
#pragma unroll
            for (int ht = 0; ht < 4; ++ht)
#pragma unroll
                for (int nt = 0; nt < 2; ++nt)
                    oacc[ht][nt] = __builtin_amdgcn_mfma_f32_16x16x16bf16_1k(av[ht], pb[mt][nt], oacc[ht][nt], 0, 0, 0);
        }
    }

    // epilogue: l directly from lacc (all rows identical); O^T/l -> vals (packed b64)
#pragma unroll
    for (int nt = 0; nt < 2; ++nt) {
        const float inv = 1.f / lacc[nt][0];
        const int srow = q0 + (w << 5) + (nt << 4) + r;
#pragma unroll
        for (int ht = 0; ht < 4; ++ht) {
            u16x4v vv;
            vv.x = f2bf(oacc[ht][nt][0] * inv);
            vv.y = f2bf(oacc[ht][nt][1] * inv);
            vv.z = f2bf(oacc[ht][nt][2] * inv);
            vv.w = f2bf(oacc[ht][nt][3] * inv);
            const int col = (h << 6) + (ht << 4) + (q << 2);
            *(u16x4v*)&vals[(rowbase + srow) * 1024 + col] = vv;
        }
    }
}

// ---------------- launcher ----------------
extern "C" void kernel_launch(void* const* d_in, const int* in_sizes, int n_in,
                              void* d_out, int out_size, void* d_ws, size_t ws_size,
                              hipStream_t stream) {
    (void)in_sizes; (void)n_in; (void)out_size; (void)ws_size;
    const float* x     = (const float*)d_in[0];   // [4,2048,1024]
    const float* w_qkv = (const float*)d_in[1];   // [3072,1024]
    const float* b_qkv = (const float*)d_in[2];   // [3072]
    const float* w_o   = (const float*)d_in[3];   // [1024,1024]
    const float* b_o   = (const float*)d_in[4];   // [1024]
    float* out = (float*)d_out;                   // [4,2048,1024]

    char* ws = (char*)d_ws;
    u16* xb    = (u16*)(ws);                          // 16 MB  [8192,1024]
    u16* wqkvb = (u16*)(ws + (size_t)(16 << 20));     //  6 MB  [3072,1024]
    u16* wob   = (u16*)(ws + (size_t)(22 << 20));     //  2 MB  [1024,1024]
    u16* qb    = (u16*)(ws + (size_t)(24 << 20));     // 16 MB  [8192,1024]
    u16* kb    = (u16*)(ws + (size_t)(40 << 20));     // 16 MB  [8192,1024]
    u16* vTb   = (u16*)(ws + (size_t)(56 << 20));     // 16 MB  [16,64,8192]
    u16* valsb = (u16*)(ws + (size_t)(72 << 20));     // 16 MB  [8192,1024]

    cast_f32_bf16<<<8192, 256, 0, stream>>>(x, xb, 2097152);
    cast_f32_bf16<<<3072, 256, 0, stream>>>(w_qkv, wqkvb, 786432);
    cast_f32_bf16<<<1024, 256, 0, stream>>>(w_o, wob, 262144);

    // qkv = x @ w_qkv^T + b_qkv -> split qb (prescaled) / kb / vT
    gemm_bt<1><<<dim3(24, 64), 256, 0, stream>>>(xb, wqkvb, b_qkv, nullptr,
                                                 qb, kb, vTb, 1024, 3072);

    // attention -> vals (bf16); grid: h fastest for XCD-local K/V reuse
    attn<<<dim3(16, 16, 4), 256, 0, stream>>>(qb, kb, vTb, valsb);

    // out = vals @ w_o^T + b_o  (fp32 out)
    gemm_bt<0><<<dim3(8, 64), 256, 0, stream>>>(valsb, wob, b_o, out,
                                                nullptr, nullptr, nullptr, 1024, 1024);
}